// Round 6
// baseline (425.291 us; speedup 1.0000x reference)
//
#include <hip/hip_runtime.h>
#include <hip/hip_bf16.h>
#include <cstdint>
#include <cstddef>

#define B_ROWS 8192
#define N_COLS 4096
#define P_BLK 8
#define D_BLK 512
#define EPSV 1e-5f

typedef __bf16 bf16x8 __attribute__((ext_vector_type(8)));
typedef float f32x4 __attribute__((ext_vector_type(4)));

// ---------------------------------------------------------------------------
// async 16B global -> LDS (HW: LDS dst = wave-uniform base + lane*16)
// ---------------------------------------------------------------------------
__device__ __forceinline__ void async_ld16(const void* g, void* l) {
    __builtin_amdgcn_global_load_lds(
        (const __attribute__((address_space(1))) void*)g,
        (__attribute__((address_space(3))) void*)l,
        16, 0, 0);
}

// ---------------------------------------------------------------------------
// block swizzle: flat id n -> (row_tile, col_tile) such that the 4 blocks
// sharing one A-slab (same row-strip, same diagonal block p) are n, n+8,
// n+16, n+24 -> same XCD under %8 round-robin.
// ---------------------------------------------------------------------------
__device__ __forceinline__ void decode_tile(int n, int& row_base, int& col_base) {
    const int row_tile = n >> 5;
    const int col_tile = ((n & 7) << 2) | ((n >> 3) & 3);
    row_base = row_tile * 128;
    col_base = col_tile * 128;
}

// ---------------------------------------------------------------------------
// pack 8 fp32 -> 8 bf16 (16B)
// ---------------------------------------------------------------------------
__device__ __forceinline__ uint4 cvt8(float4 a, float4 b) {
    union { __hip_bfloat16 hx[8]; uint4 u; } r;
    r.hx[0] = __float2bfloat16(a.x); r.hx[1] = __float2bfloat16(a.y);
    r.hx[2] = __float2bfloat16(a.z); r.hx[3] = __float2bfloat16(a.w);
    r.hx[4] = __float2bfloat16(b.x); r.hx[5] = __float2bfloat16(b.y);
    r.hx[6] = __float2bfloat16(b.z); r.hx[7] = __float2bfloat16(b.w);
    return r.u;
}

// ---------------------------------------------------------------------------
// W[p,d,e] fp32 -> Wt[p,e,d] bf16 (W1 only now; x-conversion fused into gemm1)
// block (32,8), grid (16,16,8)
// ---------------------------------------------------------------------------
__global__ __launch_bounds__(256) void tr_w_k(const float* __restrict__ W,
                                              __hip_bfloat16* __restrict__ Wt) {
    __shared__ float t[32][33];
    int p = blockIdx.z;
    int d0 = blockIdx.x * 32, e0 = blockIdx.y * 32;
    const float* Wp = W + (size_t)p * D_BLK * D_BLK;
    for (int j = 0; j < 32; j += 8) {
        int d = d0 + threadIdx.y + j;
        t[threadIdx.y + j][threadIdx.x] = Wp[(size_t)d * D_BLK + e0 + threadIdx.x];
    }
    __syncthreads();
    __hip_bfloat16* Wtp = Wt + (size_t)p * D_BLK * D_BLK;
    for (int j = 0; j < 32; j += 8) {
        int e = e0 + threadIdx.y + j;
        Wtp[(size_t)e * D_BLK + d0 + threadIdx.x] =
            __float2bfloat16(t[threadIdx.x][threadIdx.y + j]);
    }
}

// ---------------------------------------------------------------------------
// mid kernel: blocks [0,2048): W2' = a[d]*W2 transposed bf16 (a from stats);
//             blocks [2048,2176): bias2'[col] += bias2 + sum_d c[d]*W2[p,d,e]
// finalize folded in: a,c computed inline from sums/sumsq.
// ---------------------------------------------------------------------------
__global__ __launch_bounds__(256) void mid_k(const float* __restrict__ W2,
                                             const float* __restrict__ sums,
                                             const float* __restrict__ sumsq,
                                             const float* __restrict__ bnw,
                                             const float* __restrict__ bnb,
                                             const float* __restrict__ bias2,
                                             __hip_bfloat16* __restrict__ w2t,
                                             float* __restrict__ b2p) {
    __shared__ float tl[32][33];
    __shared__ float as_[32];
    const float invB = 1.0f / B_ROWS;
    if (blockIdx.x < 2048) {
        const int n = blockIdx.x;
        const int p = n >> 8;
        const int rem = n & 255;
        const int d0 = (rem & 15) * 32, e0 = (rem >> 4) * 32;
        const int tx = threadIdx.x & 31, ty = threadIdx.x >> 5;
        if (threadIdx.x < 32) {
            int idx = p * D_BLK + d0 + threadIdx.x;
            float m = sums[idx] * invB;
            float var = sumsq[idx] * invB - m * m;
            as_[threadIdx.x] = bnw[idx] * rsqrtf(var + EPSV);
        }
        __syncthreads();
        const float* Wp = W2 + (size_t)p * D_BLK * D_BLK;
        for (int j = 0; j < 32; j += 8) {
            int d = d0 + ty + j;
            tl[ty + j][tx] = Wp[(size_t)d * D_BLK + e0 + tx] * as_[ty + j];
        }
        __syncthreads();
        __hip_bfloat16* Wtp = w2t + (size_t)p * D_BLK * D_BLK;
        for (int j = 0; j < 32; j += 8) {
            int e = e0 + ty + j;
            Wtp[(size_t)e * D_BLK + d0 + tx] = __float2bfloat16(tl[tx][ty + j]);
        }
        return;
    }
    const int n2 = blockIdx.x - 2048;            // 0..127
    const int colblk = n2 & 15, chunk = n2 >> 4;
    const int col = colblk * 256 + threadIdx.x;
    const int p = col >> 9;
    const int e = col & (D_BLK - 1);
    const int d0 = chunk * 64;
    float acc = (chunk == 0) ? bias2[col] : 0.0f;
    for (int d = 0; d < 64; d++) {
        int idx = p * D_BLK + d0 + d;
        float m = sums[idx] * invB;
        float var = sumsq[idx] * invB - m * m;
        float ai = bnw[idx] * rsqrtf(var + EPSV);
        float ci = bnb[idx] - m * ai;
        acc += ci * W2[((size_t)p * D_BLK + d0 + d) * D_BLK + e];
    }
    atomicAdd(&b2p[col], acc);
}

// ---------------------------------------------------------------------------
// GEMM core (R1-proven, 95us): 128x128 tile, BK=32, double-buffered LDS with
// counted-vmcnt pipeline. UNCHANGED — serves as the control for this round.
// ---------------------------------------------------------------------------
__device__ __forceinline__ void gemm_core(const __hip_bfloat16* __restrict__ A,
                                          const __hip_bfloat16* __restrict__ Bt,
                                          int row_base, int col_base,
                                          f32x4 acc[4][4]) {
    __shared__ __hip_bfloat16 As[2][128 * 32];
    __shared__ __hip_bfloat16 Bs[2][128 * 32];

    const int tid = threadIdx.x;
    const int lane = tid & 63;
    const int wave = tid >> 6;
    const int wm = (wave >> 1) * 64;
    const int wn = (wave & 1) * 64;
    const int p = col_base >> 9;
    const int ebase = col_base & (D_BLK - 1);

    const int ar = tid >> 2;
    const int c4 = tid & 3;
    const int kq8 = (c4 ^ ((tid >> 3) & 3)) * 8;
    const int dst_off = ar * 32 + c4 * 8;

    const __hip_bfloat16* a_src0 = A + (size_t)(row_base + ar) * N_COLS + p * D_BLK + kq8;
    const __hip_bfloat16* a_src1 = a_src0 + (size_t)64 * N_COLS;
    const __hip_bfloat16* b_src0 = Bt + (size_t)(p * D_BLK + ebase + ar) * D_BLK + kq8;
    const __hip_bfloat16* b_src1 = b_src0 + (size_t)64 * D_BLK;

    const int fm = lane & 15;
    const int fkoff = ((lane >> 4) ^ ((fm >> 1) & 3)) * 8;

    for (int i = 0; i < 4; i++)
        for (int j = 0; j < 4; j++)
            acc[i][j] = (f32x4){0.0f, 0.0f, 0.0f, 0.0f};

    async_ld16(a_src0, &As[0][dst_off]);
    async_ld16(a_src1, &As[0][dst_off + 64 * 32]);
    async_ld16(b_src0, &Bs[0][dst_off]);
    async_ld16(b_src1, &Bs[0][dst_off + 64 * 32]);

    int cur = 0;
    for (int k0 = 0; k0 < D_BLK; k0 += 32) {
        if (k0 + 32 < D_BLK) {
            __hip_bfloat16* ad = &As[cur ^ 1][dst_off];
            __hip_bfloat16* bd = &Bs[cur ^ 1][dst_off];
            async_ld16(a_src0 + 32, ad);
            async_ld16(a_src1 + 32, ad + 64 * 32);
            async_ld16(b_src0 + 32, bd);
            async_ld16(b_src1 + 32, bd + 64 * 32);
            a_src0 += 32; a_src1 += 32; b_src0 += 32; b_src1 += 32;
            asm volatile("s_waitcnt vmcnt(4)" ::: "memory");
        } else {
            asm volatile("s_waitcnt vmcnt(0)" ::: "memory");
        }
        __builtin_amdgcn_s_barrier();
        asm volatile("" ::: "memory");

        bf16x8 af[4], bfr[4];
        const __hip_bfloat16* Asc = &As[cur][0];
        const __hip_bfloat16* Bsc = &Bs[cur][0];
#pragma unroll
        for (int i = 0; i < 4; i++)
            af[i] = *(const bf16x8*)&Asc[(wm + i * 16 + fm) * 32 + fkoff];
#pragma unroll
        for (int j = 0; j < 4; j++)
            bfr[j] = *(const bf16x8*)&Bsc[(wn + j * 16 + fm) * 32 + fkoff];
        asm volatile("s_waitcnt lgkmcnt(0)" ::: "memory");
        __builtin_amdgcn_sched_barrier(0);
        __builtin_amdgcn_s_barrier();
        asm volatile("" ::: "memory");

#pragma unroll
        for (int i = 0; i < 4; i++)
#pragma unroll
            for (int j = 0; j < 4; j++)
                acc[i][j] = __builtin_amdgcn_mfma_f32_16x16x32_bf16(
                    af[i], bfr[j], acc[i][j], 0, 0, 0);
        cur ^= 1;
    }
}

// ---------------------------------------------------------------------------
// GEMM1 with FUSED x->bf16 conversion: A is staged from fp32 x via
// global_load_dwordx4 -> cvt -> ds_write_b128 (identical swizzled LDS layout
// as gemm_core); B (w1t) stays global_load_lds. One of the 4 col-tile blocks
// per A-slab also stores the converted bf16 to xb (gemm2's residual input).
// This deletes prep_k's 190 MB x-pass.
//
// vmcnt discipline (robust to any intra-region issue order; regions bounded
// by "memory" fences): at top-of-step vmcnt(6), the 6 newest VMEM ops are
// A(k+1)[4] + B(k+1)[2]; everything older (B(k), xb-stores) is retired.
// ---------------------------------------------------------------------------
__global__ __launch_bounds__(256) void gemm1_k(const float* __restrict__ x,
                                               const __hip_bfloat16* __restrict__ w1t,
                                               const float* __restrict__ bias1,
                                               __hip_bfloat16* __restrict__ xb,
                                               __hip_bfloat16* __restrict__ h,
                                               float* __restrict__ sum,
                                               float* __restrict__ sumsq) {
    __shared__ __hip_bfloat16 As[2][128 * 32];
    __shared__ __hip_bfloat16 Bs[2][128 * 32];

    int row_base, col_base;
    decode_tile(blockIdx.x, row_base, col_base);

    const int tid = threadIdx.x;
    const int lane = tid & 63;
    const int wave = tid >> 6;
    const int wm = (wave >> 1) * 64;
    const int wn = (wave & 1) * 64;
    const int p = col_base >> 9;
    const int ebase = col_base & (D_BLK - 1);

    const int ar = tid >> 2;
    const int c4 = tid & 3;
    const int kq8 = (c4 ^ ((tid >> 3) & 3)) * 8;
    const int dst_off = ar * 32 + c4 * 8;
    const bool do_store = ((col_base >> 7) & 3) == 0;   // one block per A-slab

    const float* ax0 = x + (size_t)(row_base + ar) * N_COLS + p * D_BLK + kq8;
    const float* ax1 = ax0 + (size_t)64 * N_COLS;
    const __hip_bfloat16* b_src0 = w1t + (size_t)(p * D_BLK + ebase + ar) * D_BLK + kq8;
    const __hip_bfloat16* b_src1 = b_src0 + (size_t)64 * D_BLK;
    __hip_bfloat16* xs0 = xb + (size_t)(row_base + ar) * N_COLS + p * D_BLK + kq8;
    __hip_bfloat16* xs1 = xs0 + (size_t)64 * N_COLS;

    const int fm = lane & 15;
    const int fkoff = ((lane >> 4) ^ ((fm >> 1) & 3)) * 8;

    f32x4 acc[4][4];
#pragma unroll
    for (int i = 0; i < 4; i++)
#pragma unroll
        for (int j = 0; j < 4; j++)
            acc[i][j] = (f32x4){0.0f, 0.0f, 0.0f, 0.0f};

    // ---- prologue: chunk 0 (A via regs, B via gload_lds) ----
    {
        float4 a0a = *(const float4*)ax0, a0b = *(const float4*)(ax0 + 4);
        float4 a1a = *(const float4*)ax1, a1b = *(const float4*)(ax1 + 4);
        async_ld16(b_src0, &Bs[0][dst_off]);
        async_ld16(b_src1, &Bs[0][dst_off + 64 * 32]);
        ax0 += 32; ax1 += 32; b_src0 += 32; b_src1 += 32;
        uint4 r0 = cvt8(a0a, a0b);               // compiler auto-waits on A regs
        uint4 r1 = cvt8(a1a, a1b);
        *(uint4*)&As[0][dst_off] = r0;
        *(uint4*)&As[0][dst_off + 64 * 32] = r1;
        if (do_store) { *(uint4*)xs0 = r0; *(uint4*)xs1 = r1; xs0 += 32; xs1 += 32; }
        asm volatile("s_waitcnt lgkmcnt(0)" ::: "memory");  // A writes drained
    }

    int cur = 0;
#pragma unroll 2
    for (int k = 0; k < 16; ++k) {
        float4 na0a, na0b, na1a, na1b;
        if (k < 15) {
            // issue A(k+1) reg-loads FIRST, then B(k+1) gload_lds (so the
            // compiler's auto-wait at cvt time leaves B in flight)
            na0a = *(const float4*)ax0; na0b = *(const float4*)(ax0 + 4);
            na1a = *(const float4*)ax1; na1b = *(const float4*)(ax1 + 4);
            __hip_bfloat16* bd = &Bs[cur ^ 1][dst_off];
            async_ld16(b_src0, bd);
            async_ld16(b_src1, bd + 64 * 32);
            ax0 += 32; ax1 += 32; b_src0 += 32; b_src1 += 32;
            asm volatile("s_waitcnt vmcnt(6)" ::: "memory");  // B(k) done
        } else {
            asm volatile("s_waitcnt vmcnt(0)" ::: "memory");
        }
        __builtin_amdgcn_s_barrier();          // buf cur ready (A writes were
        asm volatile("" ::: "memory");         // drained pre-barrier by each wave)

        bf16x8 af[4], bfr[4];
        const __hip_bfloat16* Asc = &As[cur][0];
        const __hip_bfloat16* Bsc = &Bs[cur][0];
#pragma unroll
        for (int i = 0; i < 4; i++)
            af[i] = *(const bf16x8*)&Asc[(wm + i * 16 + fm) * 32 + fkoff];
#pragma unroll
        for (int j = 0; j < 4; j++)
            bfr[j] = *(const bf16x8*)&Bsc[(wn + j * 16 + fm) * 32 + fkoff];
        asm volatile("s_waitcnt lgkmcnt(0)" ::: "memory");
        __builtin_amdgcn_sched_barrier(0);
        __builtin_amdgcn_s_barrier();          // reads drained -> stages safe
        asm volatile("" ::: "memory");

#pragma unroll
        for (int i = 0; i < 4; i++)
#pragma unroll
            for (int j = 0; j < 4; j++)
                acc[i][j] = __builtin_amdgcn_mfma_f32_16x16x32_bf16(
                    af[i], bfr[j], acc[i][j], 0, 0, 0);

        if (k < 15) {
            // tail: convert A(k+1), write LDS (buf cur^1), optional xb store
            uint4 r0 = cvt8(na0a, na0b);
            uint4 r1 = cvt8(na1a, na1b);
            *(uint4*)&As[cur ^ 1][dst_off] = r0;
            *(uint4*)&As[cur ^ 1][dst_off + 64 * 32] = r1;
            if (do_store) { *(uint4*)xs0 = r0; *(uint4*)xs1 = r1; xs0 += 32; xs1 += 32; }
            asm volatile("s_waitcnt lgkmcnt(0)" ::: "memory");  // drain before next b1
        }
        cur ^= 1;
    }

    // ---- epilogue: bias + h store + stats ----
    const int cr = (lane >> 4) * 4;
    const int cc = lane & 15;
#pragma unroll
    for (int j = 0; j < 4; j++) {
        const int col = col_base + wn + j * 16 + cc;
        const float b1 = bias1[col];
        float s = 0.0f, sq = 0.0f;
#pragma unroll
        for (int i = 0; i < 4; i++) {
            const int row0 = row_base + wm + i * 16 + cr;
#pragma unroll
            for (int r = 0; r < 4; r++) {
                float v = acc[i][j][r] + b1;
                h[(size_t)(row0 + r) * N_COLS + col] = __float2bfloat16(v);
                s += v;
                sq += v * v;
            }
        }
        s  += __shfl_xor(s, 16);  s  += __shfl_xor(s, 32);
        sq += __shfl_xor(sq, 16); sq += __shfl_xor(sq, 32);
        if (lane < 16) {
            atomicAdd(&sum[col], s);
            atomicAdd(&sumsq[col], sq);
        }
    }
}

// ---------------------------------------------------------------------------
// GEMM2: o3 = h_bf16 @ W2' + bias2' + x ; out = (g + sig(be*o3)*(1-g)) * o3
// UNCHANGED from R1 (control).
// ---------------------------------------------------------------------------
__global__ __launch_bounds__(256) void gemm2_k(const __hip_bfloat16* __restrict__ h,
                                               const __hip_bfloat16* __restrict__ w2t,
                                               const float* __restrict__ bias2p,
                                               const __hip_bfloat16* __restrict__ xb,
                                               const float* __restrict__ gamma3,
                                               const float* __restrict__ beta3,
                                               float* __restrict__ out) {
    int row_base, col_base;
    decode_tile(blockIdx.x, row_base, col_base);

    f32x4 acc[4][4];
    gemm_core(h, w2t, row_base, col_base, acc);

    const int tid = threadIdx.x;
    const int lane = tid & 63;
    const int wave = tid >> 6;
    const int wm = (wave >> 1) * 64;
    const int wn = (wave & 1) * 64;
    const int cr = (lane >> 4) * 4;
    const int cc = lane & 15;

#pragma unroll
    for (int j = 0; j < 4; j++) {
        const int col = col_base + wn + j * 16 + cc;
        const float bb = bias2p[col];
        const float g  = gamma3[col];
        const float be = beta3[col];
#pragma unroll
        for (int i = 0; i < 4; i++) {
            const int row0 = row_base + wm + i * 16 + cr;
#pragma unroll
            for (int r = 0; r < 4; r++) {
                const size_t idx = (size_t)(row0 + r) * N_COLS + col;
                float o3 = acc[i][j][r] + bb + __bfloat162float(xb[idx]);
                float sg = __fdividef(1.0f, 1.0f + __expf(-be * o3));
                out[idx] = (g + sg * (1.0f - g)) * o3;
            }
        }
    }
}

// ---------------------------------------------------------------------------
extern "C" void kernel_launch(void* const* d_in, const int* in_sizes, int n_in,
                              void* d_out, int out_size, void* d_ws, size_t ws_size,
                              hipStream_t stream) {
    const float* x     = (const float*)d_in[0];
    const float* W1    = (const float*)d_in[1];
    const float* bias1 = (const float*)d_in[2];
    const float* W2    = (const float*)d_in[3];
    const float* bias2 = (const float*)d_in[4];
    const float* bnw   = (const float*)d_in[5];
    const float* bnb   = (const float*)d_in[6];
    const float* gam3  = (const float*)d_in[7];
    const float* bet3  = (const float*)d_in[8];
    float* out = (float*)d_out;

    // workspace layout
    char* ws = (char*)d_ws;
    const size_t XB_BYTES = (size_t)B_ROWS * N_COLS * 2;        // 64 MiB
    const size_t H_BYTES  = (size_t)B_ROWS * N_COLS * 2;        // 64 MiB
    const size_t WT_BYTES = (size_t)P_BLK * D_BLK * D_BLK * 2;  // 4 MiB
    const size_t V_BYTES  = (size_t)N_COLS * 4;                 // 16 KiB

    __hip_bfloat16* xb   = (__hip_bfloat16*)(ws);
    __hip_bfloat16* hbuf = (__hip_bfloat16*)(ws + XB_BYTES);
    __hip_bfloat16* w1t  = (__hip_bfloat16*)(ws + XB_BYTES + H_BYTES);
    __hip_bfloat16* w2t  = (__hip_bfloat16*)(ws + XB_BYTES + H_BYTES + WT_BYTES);
    float* sums  = (float*)(ws + XB_BYTES + H_BYTES + 2 * WT_BYTES);
    float* sumsq = sums + N_COLS;
    float* b2p   = sums + 2 * N_COLS;   // zeroed: mid_k accumulates via atomics

    (void)in_sizes; (void)n_in; (void)out_size; (void)ws_size;

    // zero stats accumulators + bias2' (ws is poisoned before every call)
    hipMemsetAsync(sums, 0, 3 * V_BYTES, stream);

    // W1 -> bf16 transposed [p,e,d]  (x-conversion now fused into gemm1)
    tr_w_k<<<dim3(16, 16, 8), dim3(32, 8), 0, stream>>>(W1, w1t);
    // GEMM1 (reads fp32 x directly, emits xb as side product) + bias + stats
    gemm1_k<<<dim3((B_ROWS / 128) * (N_COLS / 128)), dim3(256), 0, stream>>>(
        x, w1t, bias1, xb, hbuf, sums, sumsq);
    // W2' (scale from stats, inline finalize) + bias2' (inline c)
    mid_k<<<dim3(2048 + 128), dim3(256), 0, stream>>>(
        W2, sums, sumsq, bnw, bnb, bias2, w2t, b2p);
    // GEMM2 + residual + gate
    gemm2_k<<<dim3((B_ROWS / 128) * (N_COLS / 128)), dim3(256), 0, stream>>>(
        hbuf, w2t, b2p, xb, gam3, bet3, out);
}

// Round 7
// 389.695 us; speedup vs baseline: 1.0913x; 1.0913x over previous
//
#include <hip/hip_runtime.h>
#include <hip/hip_bf16.h>
#include <cstdint>
#include <cstddef>

#define B_ROWS 8192
#define N_COLS 4096
#define P_BLK 8
#define D_BLK 512
#define EPSV 1e-5f

typedef __bf16 bf16x8 __attribute__((ext_vector_type(8)));
typedef float f32x4 __attribute__((ext_vector_type(4)));

// ---------------------------------------------------------------------------
// async 16B global -> LDS (HW: LDS dst = wave-uniform base + lane*16)
// ---------------------------------------------------------------------------
__device__ __forceinline__ void async_ld16(const void* g, void* l) {
    __builtin_amdgcn_global_load_lds(
        (const __attribute__((address_space(1))) void*)g,
        (__attribute__((address_space(3))) void*)l,
        16, 0, 0);
}

// ---------------------------------------------------------------------------
// block swizzle: flat id n -> (row_tile, col_tile) such that the 4 blocks
// sharing one A-slab (same row-strip, same diagonal block p) are n, n+8,
// n+16, n+24 -> same XCD under %8 round-robin.
// ---------------------------------------------------------------------------
__device__ __forceinline__ void decode_tile(int n, int& row_base, int& col_base) {
    const int row_tile = n >> 5;
    const int col_tile = ((n & 7) << 2) | ((n >> 3) & 3);
    row_base = row_tile * 128;
    col_base = col_tile * 128;
}

// ---------------------------------------------------------------------------
// x fp32 -> bf16 (blocks [0,16384)) fused with W1 transpose (blocks >= 16384)
// (R1-proven prep kernel, restored verbatim)
// ---------------------------------------------------------------------------
__global__ __launch_bounds__(256) void prep_k(const float* __restrict__ x,
                                              __hip_bfloat16* __restrict__ xb,
                                              const float* __restrict__ W1,
                                              __hip_bfloat16* __restrict__ w1t) {
    __shared__ float tl[32][33];
    if (blockIdx.x < 16384) {
        size_t i = ((size_t)blockIdx.x * 256 + threadIdx.x) * 8;
        float4 v0 = *(const float4*)(x + i);
        float4 v1 = *(const float4*)(x + i + 4);
        union { __hip_bfloat16 h[8]; uint4 u; } r;
        r.h[0] = __float2bfloat16(v0.x); r.h[1] = __float2bfloat16(v0.y);
        r.h[2] = __float2bfloat16(v0.z); r.h[3] = __float2bfloat16(v0.w);
        r.h[4] = __float2bfloat16(v1.x); r.h[5] = __float2bfloat16(v1.y);
        r.h[6] = __float2bfloat16(v1.z); r.h[7] = __float2bfloat16(v1.w);
        *(uint4*)(xb + i) = r.u;
        return;
    }
    const int n = blockIdx.x - 16384;            // 0..2047
    const int p = n >> 8;
    const int rem = n & 255;
    const int d0 = (rem & 15) * 32, e0 = (rem >> 4) * 32;
    const int tx = threadIdx.x & 31, ty = threadIdx.x >> 5;
    const float* Wp = W1 + (size_t)p * D_BLK * D_BLK;
    for (int j = 0; j < 32; j += 8) {
        int d = d0 + ty + j;
        tl[ty + j][tx] = Wp[(size_t)d * D_BLK + e0 + tx];
    }
    __syncthreads();
    __hip_bfloat16* Wtp = w1t + (size_t)p * D_BLK * D_BLK;
    for (int j = 0; j < 32; j += 8) {
        int e = e0 + ty + j;
        Wtp[(size_t)e * D_BLK + d0 + tx] = __float2bfloat16(tl[tx][ty + j]);
    }
}

// ---------------------------------------------------------------------------
// mid kernel: blocks [0,2048): W2' = a[d]*W2 transposed bf16 (a from stats);
//             blocks [2048,2176): bias2'[col] += bias2 + sum_d c[d]*W2[p,d,e]
// finalize folded in: a,c computed inline from sums/sumsq.
// ---------------------------------------------------------------------------
__global__ __launch_bounds__(256) void mid_k(const float* __restrict__ W2,
                                             const float* __restrict__ sums,
                                             const float* __restrict__ sumsq,
                                             const float* __restrict__ bnw,
                                             const float* __restrict__ bnb,
                                             const float* __restrict__ bias2,
                                             __hip_bfloat16* __restrict__ w2t,
                                             float* __restrict__ b2p) {
    __shared__ float tl[32][33];
    __shared__ float as_[32];
    const float invB = 1.0f / B_ROWS;
    if (blockIdx.x < 2048) {
        const int n = blockIdx.x;
        const int p = n >> 8;
        const int rem = n & 255;
        const int d0 = (rem & 15) * 32, e0 = (rem >> 4) * 32;
        const int tx = threadIdx.x & 31, ty = threadIdx.x >> 5;
        if (threadIdx.x < 32) {
            int idx = p * D_BLK + d0 + threadIdx.x;
            float m = sums[idx] * invB;
            float var = sumsq[idx] * invB - m * m;
            as_[threadIdx.x] = bnw[idx] * rsqrtf(var + EPSV);
        }
        __syncthreads();
        const float* Wp = W2 + (size_t)p * D_BLK * D_BLK;
        for (int j = 0; j < 32; j += 8) {
            int d = d0 + ty + j;
            tl[ty + j][tx] = Wp[(size_t)d * D_BLK + e0 + tx] * as_[ty + j];
        }
        __syncthreads();
        __hip_bfloat16* Wtp = w2t + (size_t)p * D_BLK * D_BLK;
        for (int j = 0; j < 32; j += 8) {
            int e = e0 + ty + j;
            Wtp[(size_t)e * D_BLK + d0 + tx] = __float2bfloat16(tl[tx][ty + j]);
        }
        return;
    }
    const int n2 = blockIdx.x - 2048;            // 0..127
    const int colblk = n2 & 15, chunk = n2 >> 4;
    const int col = colblk * 256 + threadIdx.x;
    const int p = col >> 9;
    const int e = col & (D_BLK - 1);
    const int d0 = chunk * 64;
    float acc = (chunk == 0) ? bias2[col] : 0.0f;
    for (int d = 0; d < 64; d++) {
        int idx = p * D_BLK + d0 + d;
        float m = sums[idx] * invB;
        float var = sumsq[idx] * invB - m * m;
        float ai = bnw[idx] * rsqrtf(var + EPSV);
        float ci = bnb[idx] - m * ai;
        acc += ci * W2[((size_t)p * D_BLK + d0 + d) * D_BLK + e];
    }
    atomicAdd(&b2p[col], acc);
}

// ---------------------------------------------------------------------------
// GEMM core: 128x128 tile, BK=32, double-buffered LDS, counted-vmcnt,
// SINGLE barrier per K-step (R1 core minus the second barrier).
//
// Correctness of single barrier:
//  - Each wave arrives at barrier(k) only after its lgkmcnt(0) drained its
//    step k-1 ds_reads -> barrier(k) separates ALL reads of buf cur^1
//    (read at step k-1) from anything after it.
//  - Stage S(k+1) targets buf cur^1 and is issued AFTER barrier(k): WAR safe.
//  - vmcnt(0) at top of step k retires S(k) (the only outstanding VMEM, since
//    S(k+1) is not yet issued) before barrier(k) publishes buf cur: RAW safe.
//  Cover distance for S(k): issued post-barrier(k-1), waited at top of k
//  = one full ds_read+MFMA phase — identical to R1's counted-vmcnt placement;
//  the only delta is 16 fewer barrier drains per block.
//
// LDS bank swizzle unchanged: chunk position c of row r holds global chunk
// c^((r>>1)&3), realized by permuting the *source* address (verified: 0
// bank conflicts). LDS = 32 KB, residency as R1 (R3/R4: more residency
// thrashes L2).
// ---------------------------------------------------------------------------
__device__ __forceinline__ void gemm_core(const __hip_bfloat16* __restrict__ A,
                                          const __hip_bfloat16* __restrict__ Bt,
                                          int row_base, int col_base,
                                          f32x4 acc[4][4]) {
    __shared__ __hip_bfloat16 As[2][128 * 32];
    __shared__ __hip_bfloat16 Bs[2][128 * 32];

    const int tid = threadIdx.x;
    const int lane = tid & 63;
    const int wave = tid >> 6;
    const int wm = (wave >> 1) * 64;
    const int wn = (wave & 1) * 64;
    const int p = col_base >> 9;
    const int ebase = col_base & (D_BLK - 1);

    // staging: thread tid fills LDS row ar=tid>>2, chunk position c4=tid&3;
    // it must FETCH global chunk q4 = c4 ^ ((ar>>1)&3) = c4 ^ ((tid>>3)&3)
    const int ar = tid >> 2;
    const int c4 = tid & 3;
    const int kq8 = (c4 ^ ((tid >> 3) & 3)) * 8;   // fetched k-offset (elements)
    const int dst_off = ar * 32 + c4 * 8;          // == tid*8 elements = lane*16B

    const __hip_bfloat16* a_src0 = A + (size_t)(row_base + ar) * N_COLS + p * D_BLK + kq8;
    const __hip_bfloat16* a_src1 = a_src0 + (size_t)64 * N_COLS;
    const __hip_bfloat16* b_src0 = Bt + (size_t)(p * D_BLK + ebase + ar) * D_BLK + kq8;
    const __hip_bfloat16* b_src1 = b_src0 + (size_t)64 * D_BLK;

    // fragment read: lane wants row R=...+fm, k-chunk kq=lane>>4; its LDS chunk
    // position is kq ^ ((R>>1)&3) = kq ^ ((fm>>1)&3)
    const int fm = lane & 15;
    const int fkoff = ((lane >> 4) ^ ((fm >> 1) & 3)) * 8;

    for (int i = 0; i < 4; i++)
        for (int j = 0; j < 4; j++)
            acc[i][j] = (f32x4){0.0f, 0.0f, 0.0f, 0.0f};

    // prologue: stage K-step 0 into buffer 0 (4 loads in flight)
    async_ld16(a_src0, &As[0][dst_off]);
    async_ld16(a_src1, &As[0][dst_off + 64 * 32]);
    async_ld16(b_src0, &Bs[0][dst_off]);
    async_ld16(b_src1, &Bs[0][dst_off + 64 * 32]);
    a_src0 += 32; a_src1 += 32; b_src0 += 32; b_src1 += 32;

    int cur = 0;
    for (int k0 = 0; k0 < D_BLK; k0 += 32) {
        // S(k) is the only outstanding VMEM here -> retire it fully
        asm volatile("s_waitcnt vmcnt(0)" ::: "memory");
        __builtin_amdgcn_s_barrier();          // publishes buf cur; also all
        asm volatile("" ::: "memory");         // reads of buf cur^1 are done

        if (k0 + 32 < D_BLK) {
            // stage S(k+1) into the other buffer (WAR-safe: post-barrier)
            __hip_bfloat16* ad = &As[cur ^ 1][dst_off];
            __hip_bfloat16* bd = &Bs[cur ^ 1][dst_off];
            async_ld16(a_src0, ad);
            async_ld16(a_src1, ad + 64 * 32);
            async_ld16(b_src0, bd);
            async_ld16(b_src1, bd + 64 * 32);
            a_src0 += 32; a_src1 += 32; b_src0 += 32; b_src1 += 32;
        }

        bf16x8 af[4], bfr[4];
        const __hip_bfloat16* Asc = &As[cur][0];
        const __hip_bfloat16* Bsc = &Bs[cur][0];
#pragma unroll
        for (int i = 0; i < 4; i++)
            af[i] = *(const bf16x8*)&Asc[(wm + i * 16 + fm) * 32 + fkoff];
#pragma unroll
        for (int j = 0; j < 4; j++)
            bfr[j] = *(const bf16x8*)&Bsc[(wn + j * 16 + fm) * 32 + fkoff];
        // drain ds_reads; fence (rule #18) so MFMAs can't slide above the wait
        asm volatile("s_waitcnt lgkmcnt(0)" ::: "memory");
        __builtin_amdgcn_sched_barrier(0);

#pragma unroll
        for (int i = 0; i < 4; i++)
#pragma unroll
            for (int j = 0; j < 4; j++)
                acc[i][j] = __builtin_amdgcn_mfma_f32_16x16x32_bf16(
                    af[i], bfr[j], acc[i][j], 0, 0, 0);
        cur ^= 1;
    }
}

// ---------------------------------------------------------------------------
// GEMM1: h = xb @ W1 + bias1 (bf16 out), plus per-column sum / sumsq atomics
// ---------------------------------------------------------------------------
__global__ __launch_bounds__(256) void gemm1_k(const __hip_bfloat16* __restrict__ xb,
                                               const __hip_bfloat16* __restrict__ w1t,
                                               const float* __restrict__ bias1,
                                               __hip_bfloat16* __restrict__ h,
                                               float* __restrict__ sum,
                                               float* __restrict__ sumsq) {
    int row_base, col_base;
    decode_tile(blockIdx.x, row_base, col_base);

    f32x4 acc[4][4];
    gemm_core(xb, w1t, row_base, col_base, acc);

    const int tid = threadIdx.x;
    const int lane = tid & 63;
    const int wave = tid >> 6;
    const int wm = (wave >> 1) * 64;
    const int wn = (wave & 1) * 64;
    const int cr = (lane >> 4) * 4;   // C/D: row = quad*4 + reg
    const int cc = lane & 15;         // C/D: col = lane&15

#pragma unroll
    for (int j = 0; j < 4; j++) {
        const int col = col_base + wn + j * 16 + cc;
        const float b1 = bias1[col];
        float s = 0.0f, sq = 0.0f;
#pragma unroll
        for (int i = 0; i < 4; i++) {
            const int row0 = row_base + wm + i * 16 + cr;
#pragma unroll
            for (int r = 0; r < 4; r++) {
                float v = acc[i][j][r] + b1;
                h[(size_t)(row0 + r) * N_COLS + col] = __float2bfloat16(v);
                s += v;
                sq += v * v;
            }
        }
        s  += __shfl_xor(s, 16);  s  += __shfl_xor(s, 32);
        sq += __shfl_xor(sq, 16); sq += __shfl_xor(sq, 32);
        if (lane < 16) {
            atomicAdd(&sum[col], s);
            atomicAdd(&sumsq[col], sq);
        }
    }
}

// ---------------------------------------------------------------------------
// GEMM2: o3 = h_bf16 @ W2' + bias2' + x ; out = (g + sig(be*o3)*(1-g)) * o3
// residual read from the bf16 copy xb. __expf sigmoid (R1-proven).
// ---------------------------------------------------------------------------
__global__ __launch_bounds__(256) void gemm2_k(const __hip_bfloat16* __restrict__ h,
                                               const __hip_bfloat16* __restrict__ w2t,
                                               const float* __restrict__ bias2p,
                                               const __hip_bfloat16* __restrict__ xb,
                                               const float* __restrict__ gamma3,
                                               const float* __restrict__ beta3,
                                               float* __restrict__ out) {
    int row_base, col_base;
    decode_tile(blockIdx.x, row_base, col_base);

    f32x4 acc[4][4];
    gemm_core(h, w2t, row_base, col_base, acc);

    const int tid = threadIdx.x;
    const int lane = tid & 63;
    const int wave = tid >> 6;
    const int wm = (wave >> 1) * 64;
    const int wn = (wave & 1) * 64;
    const int cr = (lane >> 4) * 4;
    const int cc = lane & 15;

#pragma unroll
    for (int j = 0; j < 4; j++) {
        const int col = col_base + wn + j * 16 + cc;
        const float bb = bias2p[col];
        const float g  = gamma3[col];
        const float be = beta3[col];
#pragma unroll
        for (int i = 0; i < 4; i++) {
            const int row0 = row_base + wm + i * 16 + cr;
#pragma unroll
            for (int r = 0; r < 4; r++) {
                const size_t idx = (size_t)(row0 + r) * N_COLS + col;
                float o3 = acc[i][j][r] + bb + __bfloat162float(xb[idx]);
                float sg = __fdividef(1.0f, 1.0f + __expf(-be * o3));
                out[idx] = (g + sg * (1.0f - g)) * o3;
            }
        }
    }
}

// ---------------------------------------------------------------------------
extern "C" void kernel_launch(void* const* d_in, const int* in_sizes, int n_in,
                              void* d_out, int out_size, void* d_ws, size_t ws_size,
                              hipStream_t stream) {
    const float* x     = (const float*)d_in[0];
    const float* W1    = (const float*)d_in[1];
    const float* bias1 = (const float*)d_in[2];
    const float* W2    = (const float*)d_in[3];
    const float* bias2 = (const float*)d_in[4];
    const float* bnw   = (const float*)d_in[5];
    const float* bnb   = (const float*)d_in[6];
    const float* gam3  = (const float*)d_in[7];
    const float* bet3  = (const float*)d_in[8];
    float* out = (float*)d_out;

    // workspace layout
    char* ws = (char*)d_ws;
    const size_t XB_BYTES = (size_t)B_ROWS * N_COLS * 2;        // 64 MiB
    const size_t H_BYTES  = (size_t)B_ROWS * N_COLS * 2;        // 64 MiB
    const size_t WT_BYTES = (size_t)P_BLK * D_BLK * D_BLK * 2;  // 4 MiB
    const size_t V_BYTES  = (size_t)N_COLS * 4;                 // 16 KiB

    __hip_bfloat16* xb   = (__hip_bfloat16*)(ws);
    __hip_bfloat16* hbuf = (__hip_bfloat16*)(ws + XB_BYTES);
    __hip_bfloat16* w1t  = (__hip_bfloat16*)(ws + XB_BYTES + H_BYTES);
    __hip_bfloat16* w2t  = (__hip_bfloat16*)(ws + XB_BYTES + H_BYTES + WT_BYTES);
    float* sums  = (float*)(ws + XB_BYTES + H_BYTES + 2 * WT_BYTES);
    float* sumsq = sums + N_COLS;
    float* b2p   = sums + 2 * N_COLS;   // zeroed: mid_k accumulates via atomics

    (void)in_sizes; (void)n_in; (void)out_size; (void)ws_size;

    // zero stats accumulators + bias2' (ws is poisoned before every call)
    hipMemsetAsync(sums, 0, 3 * V_BYTES, stream);

    // x -> bf16  fused with  W1 -> bf16 transposed [p,e,d]
    prep_k<<<dim3(16384 + 2048), dim3(256), 0, stream>>>(x, xb, W1, w1t);
    // GEMM1 + bias + stats
    gemm1_k<<<dim3((B_ROWS / 128) * (N_COLS / 128)), dim3(256), 0, stream>>>(
        xb, w1t, bias1, hbuf, sums, sumsq);
    // W2' (scale from stats, inline finalize) + bias2' (inline c)
    mid_k<<<dim3(2048 + 128), dim3(256), 0, stream>>>(
        W2, sums, sumsq, bnw, bnb, bias2, w2t, b2p);
    // GEMM2 + residual + gate
    gemm2_k<<<dim3((B_ROWS / 128) * (N_COLS / 128)), dim3(256), 0, stream>>>(
        hbuf, w2t, b2p, xb, gam3, bet3, out);
}